// Round 6
// baseline (342.184 us; speedup 1.0000x reference)
//
#include <hip/hip_runtime.h>
#include <hip/hip_bf16.h>

typedef __attribute__((ext_vector_type(4))) float f32x4;
typedef __attribute__((ext_vector_type(8))) short s16x8;
typedef __attribute__((ext_vector_type(4))) short s16x4;

#define AS1 __attribute__((address_space(1)))
#define AS3 __attribute__((address_space(3)))

__device__ __forceinline__ short f2bf(float f) {
    union { float f; unsigned u; } a; a.f = f;
    unsigned r = a.u + 0x7fff + ((a.u >> 16) & 1);
    return (short)(r >> 16);
}

__device__ __forceinline__ unsigned pk_bf16(float a, float b) {
    unsigned r;
    asm("v_cvt_pk_bf16_f32 %0, %1, %2" : "=v"(r) : "v"(a), "v"(b));
    return r;
}

// ---------------- conversion kernels ----------------

__global__ __launch_bounds__(256) void convert_f32_bf16(const float* __restrict__ in,
                                                        short* __restrict__ out, int n4) {
    int i = blockIdx.x * 256 + threadIdx.x;
    if (i < n4) {
        f32x4 v = *(const f32x4*)(in + (long)i * 4);
        s16x4 o;
        o.x = f2bf(v.x); o.y = f2bf(v.y); o.z = f2bf(v.z); o.w = f2bf(v.w);
        *(s16x4*)(out + (long)i * 4) = o;
    }
}

// src [K][N] f32 -> dst [N][K] bf16
__global__ __launch_bounds__(256) void transpose_w(const float* __restrict__ src,
                                                   short* __restrict__ dst, int K, int N) {
    __shared__ short t[64][65];
    int k0 = blockIdx.x * 64, n0 = blockIdx.y * 64;
    int tid = threadIdx.x;
    for (int i = tid; i < 64 * 64; i += 256) {
        int r = i >> 6, c = i & 63;
        t[r][c] = f2bf(src[(long)(k0 + r) * N + n0 + c]);
    }
    __syncthreads();
    for (int i = tid; i < 64 * 64; i += 256) {
        int r = i >> 6, c = i & 63;
        dst[(long)(n0 + r) * K + k0 + c] = t[c][r];
    }
}

// vp [g][1024][64] -> vt [g][64][1024] (V^T per head)
__global__ __launch_bounds__(256) void transpose_vp(const short* __restrict__ vp,
                                                    short* __restrict__ vt) {
    __shared__ short t[64][72];
    int t0 = blockIdx.x * 64;
    int g = blockIdx.y;
    int tid = threadIdx.x;
#pragma unroll
    for (int i = 0; i < 2; ++i) {
        int j = tid + i * 256;
        int r = j >> 3, c = j & 7;
        s16x8 v = *(const s16x8*)(vp + ((long)g * 1024 + t0 + r) * 64 + c * 8);
#pragma unroll
        for (int e = 0; e < 8; ++e) t[c * 8 + e][r] = v[e];
    }
    __syncthreads();
#pragma unroll
    for (int i = 0; i < 2; ++i) {
        int j = tid + i * 256;
        int r = j >> 3, c = j & 7;
        *(s16x8*)(vt + ((long)g * 64 + r) * 1024 + t0 + c * 8) = *(const s16x8*)&t[r][c * 8];
    }
}

// ---------------- GEMM: C = A @ BT^T + bias ----------------
// MODE 0: f32 out + bias.
// MODE 1: bf16 out scattered into per-head packed q/k/v [g][1024][64]; q scaled.

template <int MODE>
__global__ __launch_bounds__(256) void gemm_bt(const short* __restrict__ A,
                                               const short* __restrict__ BT,
                                               const float* __restrict__ bias,
                                               float* __restrict__ outF,
                                               short* __restrict__ q_,
                                               short* __restrict__ k_,
                                               short* __restrict__ v_,
                                               int M, int N, int K) {
    __shared__ short lA[128 * 32];
    __shared__ short lB[128 * 32];
    int tid = threadIdx.x;
    int lane = tid & 63, w = tid >> 6;
    int wr = w >> 1, wc = w & 1;
    int lo = lane & 15, hi = lane >> 4;
    int m0 = blockIdx.y * 128, n0 = blockIdx.x * 128;

    f32x4 acc[4][4];
#pragma unroll
    for (int i = 0; i < 4; ++i)
#pragma unroll
        for (int j = 0; j < 4; ++j) acc[i][j] = (f32x4){0.f, 0.f, 0.f, 0.f};

    const short* Abase = A + (long)m0 * K;
    const short* Bbase = BT + (long)n0 * K;

    for (int k0 = 0; k0 < K; k0 += 32) {
        __syncthreads();
#pragma unroll
        for (int i = 0; i < 2; ++i) {
            int c = (w * 2 + i) * 64 + lane;
            const short* ga = Abase + (long)(c >> 2) * K + k0 + (c & 3) * 8;
            const short* gb = Bbase + (long)(c >> 2) * K + k0 + (c & 3) * 8;
            __builtin_amdgcn_global_load_lds((const AS1 void*)ga,
                                             (AS3 void*)(lA + (w * 2 + i) * 512), 16, 0, 0);
            __builtin_amdgcn_global_load_lds((const AS1 void*)gb,
                                             (AS3 void*)(lB + (w * 2 + i) * 512), 16, 0, 0);
        }
        __syncthreads();

        s16x8 a[4], b[4];
#pragma unroll
        for (int mi = 0; mi < 4; ++mi)
            a[mi] = *(const s16x8*)(lA + (wr * 64 + mi * 16 + lo) * 32 + hi * 8);
#pragma unroll
        for (int ni = 0; ni < 4; ++ni)
            b[ni] = *(const s16x8*)(lB + (wc * 64 + ni * 16 + lo) * 32 + hi * 8);
#pragma unroll
        for (int mi = 0; mi < 4; ++mi)
#pragma unroll
            for (int ni = 0; ni < 4; ++ni)
                acc[mi][ni] = __builtin_amdgcn_mfma_f32_16x16x32_bf16(a[mi], b[ni], acc[mi][ni], 0, 0, 0);
    }

#pragma unroll
    for (int mi = 0; mi < 4; ++mi)
#pragma unroll
        for (int ni = 0; ni < 4; ++ni)
#pragma unroll
            for (int r = 0; r < 4; ++r) {
                int gm = m0 + wr * 64 + mi * 16 + hi * 4 + r;
                int gn = n0 + wc * 64 + ni * 16 + lo;
                float v = acc[mi][ni][r] + bias[gn];
                if (MODE == 1) {
                    int part = gn / 768;
                    int hh = (gn - part * 768) >> 6;
                    int dd = gn & 63;
                    long gi = (((long)(gm >> 10) * 12 + hh) * 1024 + (gm & 1023)) * 64 + dd;
                    if (part == 0) q_[gi] = f2bf(v * 0.180336880f);  // (1/8)*log2(e)
                    else if (part == 1) k_[gi] = f2bf(v);
                    else v_[gi] = f2bf(v);
                } else {
                    outF[(long)gm * N + gn] = v;
                }
            }
}

// ---------------- flash attention v6: zero-LDS, packed Q/K, reg-prefetched ----------------

__device__ __forceinline__ void attn_frag(const short* __restrict__ qpk,
                                          const short* __restrict__ kpk,
                                          const short* __restrict__ vbase,
                                          short* __restrict__ y,
                                          long g, long rowbase, int qb0, int h,
                                          int lo, int hi, int hi2, int sA, int sB) {
    // Q B-frag: lane holds Q[q=qb0+lo][d=kc*32+hi*8+e]
    const short* qrow = qpk + (g * 1024 + qb0 + lo) * 64;
    s16x8 bq0 = *(const s16x8*)(qrow + hi * 8);
    s16x8 bq1 = *(const s16x8*)(qrow + 32 + hi * 8);
    const short* kb = kpk + g * 65536;

    f32x4 ov[4];   // O^T: d = nd*16+hi*4+r, q = qb0+lo
#pragma unroll
    for (int nd = 0; nd < 4; ++nd) ov[nd] = (f32x4){0.f, 0.f, 0.f, 0.f};
    float mrun = -3.0e38f, lrun = 0.f;

    int kvEnd = qb0 + 16;

    // prologue: K fragments for tile 0
    s16x8 kc0[4], kc1[4];
#pragma unroll
    for (int n = 0; n < 4; ++n) {
        const short* kr = kb + (long)(n * 16 + lo) * 64;
        kc0[n] = *(const s16x8*)(kr + hi * 8);
        kc1[n] = *(const s16x8*)(kr + 32 + hi * 8);
    }

    for (int kv0 = 0; kv0 < kvEnd; kv0 += 64) {
        bool notlast = (kv0 + 64) < kvEnd;
        // prefetch next tile's K (first half) early: hides L2 latency under this tile
        s16x8 kn0[4], kn1[4];
        if (notlast) {
#pragma unroll
            for (int n = 0; n < 4; ++n)
                kn0[n] = *(const s16x8*)(kb + (long)(kv0 + 64 + n * 16 + lo) * 64 + hi * 8);
        }
        // V for current tile issued early: completes during softmax
        s16x8 av0[4], av1[4];
#pragma unroll
        for (int nd = 0; nd < 4; ++nd) {
            const short* vr = vbase + (long)(nd * 16 + lo) * 1024 + kv0;
            av0[nd] = *(const s16x8*)(vr + hi * 8);
            av1[nd] = *(const s16x8*)(vr + 32 + hi * 8);
        }

        // S^T = K Q^T : lane holds S[kv=n*16+hi*4+r][q=lo]
        f32x4 s[4];
#pragma unroll
        for (int n = 0; n < 4; ++n) {
            f32x4 t = (f32x4){0.f, 0.f, 0.f, 0.f};
            t = __builtin_amdgcn_mfma_f32_16x16x32_bf16(kc0[n], bq0, t, 0, 0, 0);
            t = __builtin_amdgcn_mfma_f32_16x16x32_bf16(kc1[n], bq1, t, 0, 0, 0);
            s[n] = t;
        }
        // second half of next K prefetch (kc1 regs just died)
        if (notlast) {
#pragma unroll
            for (int n = 0; n < 4; ++n)
                kn1[n] = *(const s16x8*)(kb + (long)(kv0 + 64 + n * 16 + lo) * 64 + 32 + hi * 8);
        }

        int qglob = qb0 + lo;
        if (kv0 + 63 > qb0) {   // diagonal tile
#pragma unroll
            for (int n = 0; n < 4; ++n)
#pragma unroll
                for (int r = 0; r < 4; ++r)
                    if (kv0 + n * 16 + hi * 4 + r > qglob) s[n][r] = -3.0e38f;
        }
        float mx = s[0][0];
#pragma unroll
        for (int n = 0; n < 4; ++n)
#pragma unroll
            for (int r = 0; r < 4; ++r) mx = fmaxf(mx, s[n][r]);
        mx = fmaxf(mx, __shfl_xor(mx, 16));
        mx = fmaxf(mx, __shfl_xor(mx, 32));
        float mn = fmaxf(mrun, mx);
        float alpha = exp2f(mrun - mn);
        mrun = mn;
        float rs = 0.f;
#pragma unroll
        for (int n = 0; n < 4; ++n)
#pragma unroll
            for (int r = 0; r < 4; ++r) {
                float p = exp2f(s[n][r] - mn);
                s[n][r] = p;
                rs += p;
            }
        rs += __shfl_xor(rs, 16);
        rs += __shfl_xor(rs, 32);
        lrun = lrun * alpha + rs;
#pragma unroll
        for (int nd = 0; nd < 4; ++nd)
#pragma unroll
            for (int r = 0; r < 4; ++r) ov[nd][r] *= alpha;

        // pack P rows to bf16 pairs: W[n][w2] covers kv = n*16+hi*4 + {2w2, 2w2+1}
        unsigned W[4][2];
#pragma unroll
        for (int n = 0; n < 4; ++n) {
            W[n][0] = pk_bf16(s[n][0], s[n][1]);
            W[n][1] = pk_bf16(s[n][2], s[n][3]);
        }
        // exchange: frag word j = W[kc*2+(hi>>1)][j&1] from lane ((hi&1)*2+(j>>1))*16+lo
        s16x8 ap[2];
#pragma unroll
        for (int kc = 0; kc < 2; ++kc) {
            unsigned a0 = __shfl(W[kc * 2][0], sA), b0 = __shfl(W[kc * 2 + 1][0], sA);
            unsigned a1 = __shfl(W[kc * 2][1], sA), b1 = __shfl(W[kc * 2 + 1][1], sA);
            unsigned a2 = __shfl(W[kc * 2][0], sB), b2 = __shfl(W[kc * 2 + 1][0], sB);
            unsigned a3 = __shfl(W[kc * 2][1], sB), b3 = __shfl(W[kc * 2 + 1][1], sB);
            union { unsigned u[4]; s16x8 v; } cv;
            cv.u[0] = hi2 ? b0 : a0;
            cv.u[1] = hi2 ? b1 : a1;
            cv.u[2] = hi2 ? b2 : a2;
            cv.u[3] = hi2 ? b3 : a3;
            ap[kc] = cv.v;
        }
        // O^T += V^T P^T
#pragma unroll
        for (int nd = 0; nd < 4; ++nd) {
            ov[nd] = __builtin_amdgcn_mfma_f32_16x16x32_bf16(av0[nd], ap[0], ov[nd], 0, 0, 0);
            ov[nd] = __builtin_amdgcn_mfma_f32_16x16x32_bf16(av1[nd], ap[1], ov[nd], 0, 0, 0);
        }
        // rotate prefetched K into current
        if (notlast) {
#pragma unroll
            for (int n = 0; n < 4; ++n) { kc0[n] = kn0[n]; kc1[n] = kn1[n]; }
        }
    }

    // epilogue: y[q][h*64+d] = O^T[d][q] / l[q]
    float inv = 1.0f / lrun;
    long row = (rowbase + qb0 + lo) * 768 + h * 64;
#pragma unroll
    for (int nd = 0; nd < 4; ++nd)
#pragma unroll
        for (int j2 = 0; j2 < 2; ++j2) {
            unsigned pv = pk_bf16(ov[nd][2 * j2] * inv, ov[nd][2 * j2 + 1] * inv);
            *(unsigned*)(y + row + nd * 16 + hi * 4 + 2 * j2) = pv;
        }
}

// grid 1536 (d = qp*192 + g -> d%8 == g%8: all q-blocks of a head on one XCD),
// 4 independent waves/block; each wave does paired fragments qp and 15-qp (17 tile-units).
__global__ __launch_bounds__(256, 3) void flash_attn6(const short* __restrict__ qpk,
                                                      const short* __restrict__ kpk,
                                                      const short* __restrict__ vtg,
                                                      short* __restrict__ y) {
    int d = blockIdx.x;
    int qp = d / 192;            // 0..7
    int g = d % 192;             // head-group
    int h = g % 12, b = g / 12;
    int tid = threadIdx.x;
    int lane = tid & 63, w = tid >> 6;
    int lo = lane & 15, hi = lane >> 4;
    int hi2 = hi >> 1;
    long rowbase = (long)b * 1024;
    const short* vbase = vtg + (long)g * 65536;
    int sA = ((hi & 1) * 2) * 16 + lo;
    int sB = sA + 16;

    attn_frag(qpk, kpk, vbase, y, g, rowbase, qp * 64 + w * 16, h, lo, hi, hi2, sA, sB);
    attn_frag(qpk, kpk, vbase, y, g, rowbase, (15 - qp) * 64 + w * 16, h, lo, hi, hi2, sA, sB);
}

// ---------------- launch ----------------

extern "C" void kernel_launch(void* const* d_in, const int* in_sizes, int n_in,
                              void* d_out, int out_size, void* d_ws, size_t ws_size,
                              hipStream_t stream) {
    const float* x      = (const float*)d_in[0];
    const float* w_attn = (const float*)d_in[1];
    const float* b_attn = (const float*)d_in[2];
    const float* w_proj = (const float*)d_in[3];
    const float* b_proj = (const float*)d_in[4];

    char* ws = (char*)d_ws;
    short* x_bf = (short*)ws;                      // 25165824 B (aliased as vt after gemm1)
    short* qpk  = (short*)(ws + 25165824);         // 25165824 B  q packed [g][1024][64]
    short* kpk  = (short*)(ws + 50331648);         // 25165824 B  k packed [g][1024][64]
    short* vpk  = (short*)(ws + 75497472);         // 25165824 B  v packed [g][1024][64]
    short* yb   = (short*)(ws + 100663296);        // 25165824 B
    short* waT  = (short*)(ws + 125829120);        // 3538944 B
    short* wpT  = (short*)(ws + 129368064);        // 1179648 B
    short* vt   = x_bf;                            // alias: x_bf dead after gemm1

    // x -> bf16
    convert_f32_bf16<<<dim3(12288), dim3(256), 0, stream>>>(x, x_bf, 3145728);
    // weight transposes (to [N][K] bf16)
    transpose_w<<<dim3(12, 36), dim3(256), 0, stream>>>(w_attn, waT, 768, 2304);
    transpose_w<<<dim3(12, 12), dim3(256), 0, stream>>>(w_proj, wpT, 768, 768);
    // QKV projection (+bias), scatter to per-head packed q/k/v (q scaled by 1/8*log2e)
    gemm_bt<1><<<dim3(18, 128), dim3(256), 0, stream>>>(x_bf, waT, b_attn,
                                                        (float*)nullptr, qpk, kpk, vpk,
                                                        16384, 2304, 768);
    // V^T per head
    transpose_vp<<<dim3(16, 192), dim3(256), 0, stream>>>(vpk, vt);
    // causal flash attention (zero-LDS, balanced split, reg-prefetched)
    flash_attn6<<<dim3(1536), dim3(256), 0, stream>>>(qpk, kpk, vt, yb);
    // output projection -> fp32
    gemm_bt<0><<<dim3(6, 128), dim3(256), 0, stream>>>(yb, wpT, b_proj,
                                                       (float*)d_out, (short*)nullptr,
                                                       (short*)nullptr, (short*)nullptr,
                                                       16384, 768, 768);
}

// Round 7
// 238.078 us; speedup vs baseline: 1.4373x; 1.4373x over previous
//
#include <hip/hip_runtime.h>
#include <hip/hip_bf16.h>

typedef __attribute__((ext_vector_type(4))) float f32x4;
typedef __attribute__((ext_vector_type(8))) short s16x8;
typedef __attribute__((ext_vector_type(4))) short s16x4;

#define AS1 __attribute__((address_space(1)))
#define AS3 __attribute__((address_space(3)))

__device__ __forceinline__ short f2bf(float f) {
    union { float f; unsigned u; } a; a.f = f;
    unsigned r = a.u + 0x7fff + ((a.u >> 16) & 1);
    return (short)(r >> 16);
}

__device__ __forceinline__ unsigned pk_bf16(float a, float b) {
    unsigned r;
    asm("v_cvt_pk_bf16_f32 %0, %1, %2" : "=v"(r) : "v"(a), "v"(b));
    return r;
}

// ---------------- conversion kernels ----------------

__global__ __launch_bounds__(256) void convert_f32_bf16(const float* __restrict__ in,
                                                        short* __restrict__ out, int n4) {
    int i = blockIdx.x * 256 + threadIdx.x;
    if (i < n4) {
        f32x4 v = *(const f32x4*)(in + (long)i * 4);
        s16x4 o;
        o.x = f2bf(v.x); o.y = f2bf(v.y); o.z = f2bf(v.z); o.w = f2bf(v.w);
        *(s16x4*)(out + (long)i * 4) = o;
    }
}

// src [K][N] f32 -> dst [N][K] bf16
__global__ __launch_bounds__(256) void transpose_w(const float* __restrict__ src,
                                                   short* __restrict__ dst, int K, int N) {
    __shared__ short t[64][65];
    int k0 = blockIdx.x * 64, n0 = blockIdx.y * 64;
    int tid = threadIdx.x;
    for (int i = tid; i < 64 * 64; i += 256) {
        int r = i >> 6, c = i & 63;
        t[r][c] = f2bf(src[(long)(k0 + r) * N + n0 + c]);
    }
    __syncthreads();
    for (int i = tid; i < 64 * 64; i += 256) {
        int r = i >> 6, c = i & 63;
        dst[(long)(n0 + r) * K + k0 + c] = t[c][r];
    }
}

// vp [g][1024][64] -> vt [g][64][1024] (V^T per head)
__global__ __launch_bounds__(256) void transpose_vp(const short* __restrict__ vp,
                                                    short* __restrict__ vt) {
    __shared__ short t[64][72];
    int t0 = blockIdx.x * 64;
    int g = blockIdx.y;
    int tid = threadIdx.x;
#pragma unroll
    for (int i = 0; i < 2; ++i) {
        int j = tid + i * 256;
        int r = j >> 3, c = j & 7;
        s16x8 v = *(const s16x8*)(vp + ((long)g * 1024 + t0 + r) * 64 + c * 8);
#pragma unroll
        for (int e = 0; e < 8; ++e) t[c * 8 + e][r] = v[e];
    }
    __syncthreads();
#pragma unroll
    for (int i = 0; i < 2; ++i) {
        int j = tid + i * 256;
        int r = j >> 3, c = j & 7;
        *(s16x8*)(vt + ((long)g * 64 + r) * 1024 + t0 + c * 8) = *(const s16x8*)&t[r][c * 8];
    }
}

// ---------------- GEMM: C = A @ BT^T + bias ----------------
// MODE 0: f32 out + bias.
// MODE 1: bf16 out scattered into per-head packed q/k/v [g][1024][64]; q scaled.

template <int MODE>
__global__ __launch_bounds__(256) void gemm_bt(const short* __restrict__ A,
                                               const short* __restrict__ BT,
                                               const float* __restrict__ bias,
                                               float* __restrict__ outF,
                                               short* __restrict__ q_,
                                               short* __restrict__ k_,
                                               short* __restrict__ v_,
                                               int M, int N, int K) {
    __shared__ short lA[128 * 32];
    __shared__ short lB[128 * 32];
    int tid = threadIdx.x;
    int lane = tid & 63, w = tid >> 6;
    int wr = w >> 1, wc = w & 1;
    int lo = lane & 15, hi = lane >> 4;
    int m0 = blockIdx.y * 128, n0 = blockIdx.x * 128;

    f32x4 acc[4][4];
#pragma unroll
    for (int i = 0; i < 4; ++i)
#pragma unroll
        for (int j = 0; j < 4; ++j) acc[i][j] = (f32x4){0.f, 0.f, 0.f, 0.f};

    const short* Abase = A + (long)m0 * K;
    const short* Bbase = BT + (long)n0 * K;

    for (int k0 = 0; k0 < K; k0 += 32) {
        __syncthreads();
#pragma unroll
        for (int i = 0; i < 2; ++i) {
            int c = (w * 2 + i) * 64 + lane;
            const short* ga = Abase + (long)(c >> 2) * K + k0 + (c & 3) * 8;
            const short* gb = Bbase + (long)(c >> 2) * K + k0 + (c & 3) * 8;
            __builtin_amdgcn_global_load_lds((const AS1 void*)ga,
                                             (AS3 void*)(lA + (w * 2 + i) * 512), 16, 0, 0);
            __builtin_amdgcn_global_load_lds((const AS1 void*)gb,
                                             (AS3 void*)(lB + (w * 2 + i) * 512), 16, 0, 0);
        }
        __syncthreads();

        s16x8 a[4], b[4];
#pragma unroll
        for (int mi = 0; mi < 4; ++mi)
            a[mi] = *(const s16x8*)(lA + (wr * 64 + mi * 16 + lo) * 32 + hi * 8);
#pragma unroll
        for (int ni = 0; ni < 4; ++ni)
            b[ni] = *(const s16x8*)(lB + (wc * 64 + ni * 16 + lo) * 32 + hi * 8);
#pragma unroll
        for (int mi = 0; mi < 4; ++mi)
#pragma unroll
            for (int ni = 0; ni < 4; ++ni)
                acc[mi][ni] = __builtin_amdgcn_mfma_f32_16x16x32_bf16(a[mi], b[ni], acc[mi][ni], 0, 0, 0);
    }

#pragma unroll
    for (int mi = 0; mi < 4; ++mi)
#pragma unroll
        for (int ni = 0; ni < 4; ++ni)
#pragma unroll
            for (int r = 0; r < 4; ++r) {
                int gm = m0 + wr * 64 + mi * 16 + hi * 4 + r;
                int gn = n0 + wc * 64 + ni * 16 + lo;
                float v = acc[mi][ni][r] + bias[gn];
                if (MODE == 1) {
                    int part = gn / 768;
                    int hh = (gn - part * 768) >> 6;
                    int dd = gn & 63;
                    long gi = (((long)(gm >> 10) * 12 + hh) * 1024 + (gm & 1023)) * 64 + dd;
                    if (part == 0) q_[gi] = f2bf(v * 0.180336880f);  // (1/8)*log2(e)
                    else if (part == 1) k_[gi] = f2bf(v);
                    else v_[gi] = f2bf(v);
                } else {
                    outF[(long)gm * N + gn] = v;
                }
            }
}

// ---------------- flash attention v7: DMA-staged shared KV tiles, swizzled LDS ----------------

__device__ __forceinline__ void attn_tile(const short* __restrict__ Kb,
                                          const short* __restrict__ Vb,
                                          int kv0, int qb0, bool diag,
                                          s16x8 bq0, s16x8 bq1,
                                          f32x4 (&ov)[4], float& mrun, float& lrun,
                                          int lo, int hi, int hi2, int sA, int sB,
                                          int sl0, int sl1) {
    // S^T = K Q^T : lane holds S[kv=n*16+hi*4+r][q=lo]
    f32x4 s[4];
#pragma unroll
    for (int n = 0; n < 4; ++n) {
        const short* kr = Kb + (n * 16 + lo) * 64;
        s16x8 kf0 = *(const s16x8*)(kr + sl0);
        s16x8 kf1 = *(const s16x8*)(kr + sl1);
        f32x4 t = (f32x4){0.f, 0.f, 0.f, 0.f};
        t = __builtin_amdgcn_mfma_f32_16x16x32_bf16(kf0, bq0, t, 0, 0, 0);
        t = __builtin_amdgcn_mfma_f32_16x16x32_bf16(kf1, bq1, t, 0, 0, 0);
        s[n] = t;
    }
    // V fragment reads issued early: ds_read latency hides under softmax
    s16x8 av0[4], av1[4];
#pragma unroll
    for (int nd = 0; nd < 4; ++nd) {
        const short* vr = Vb + (nd * 16 + lo) * 64;
        av0[nd] = *(const s16x8*)(vr + sl0);
        av1[nd] = *(const s16x8*)(vr + sl1);
    }

    int qglob = qb0 + lo;
    if (diag) {
#pragma unroll
        for (int n = 0; n < 4; ++n)
#pragma unroll
            for (int r = 0; r < 4; ++r)
                if (kv0 + n * 16 + hi * 4 + r > qglob) s[n][r] = -3.0e38f;
    }
    float mx = s[0][0];
#pragma unroll
    for (int n = 0; n < 4; ++n)
#pragma unroll
        for (int r = 0; r < 4; ++r) mx = fmaxf(mx, s[n][r]);
    mx = fmaxf(mx, __shfl_xor(mx, 16));
    mx = fmaxf(mx, __shfl_xor(mx, 32));
    float mn = fmaxf(mrun, mx);
    float alpha = exp2f(mrun - mn);
    mrun = mn;
    float rs = 0.f;
#pragma unroll
    for (int n = 0; n < 4; ++n)
#pragma unroll
        for (int r = 0; r < 4; ++r) {
            float p = exp2f(s[n][r] - mn);
            s[n][r] = p;
            rs += p;
        }
    rs += __shfl_xor(rs, 16);
    rs += __shfl_xor(rs, 32);
    lrun = lrun * alpha + rs;
#pragma unroll
    for (int nd = 0; nd < 4; ++nd)
#pragma unroll
        for (int r = 0; r < 4; ++r) ov[nd][r] *= alpha;

    // pack P rows to bf16 pairs: W[n][w2] covers kv = n*16+hi*4 + {2w2, 2w2+1}
    unsigned W[4][2];
#pragma unroll
    for (int n = 0; n < 4; ++n) {
        W[n][0] = pk_bf16(s[n][0], s[n][1]);
        W[n][1] = pk_bf16(s[n][2], s[n][3]);
    }
    // exchange: frag word j = W[kc*2+(hi>>1)][j&1] from lane ((hi&1)*2+(j>>1))*16+lo
    s16x8 ap[2];
#pragma unroll
    for (int kc = 0; kc < 2; ++kc) {
        unsigned a0 = __shfl(W[kc * 2][0], sA), b0 = __shfl(W[kc * 2 + 1][0], sA);
        unsigned a1 = __shfl(W[kc * 2][1], sA), b1 = __shfl(W[kc * 2 + 1][1], sA);
        unsigned a2 = __shfl(W[kc * 2][0], sB), b2 = __shfl(W[kc * 2 + 1][0], sB);
        unsigned a3 = __shfl(W[kc * 2][1], sB), b3 = __shfl(W[kc * 2 + 1][1], sB);
        union { unsigned u[4]; s16x8 v; } cv;
        cv.u[0] = hi2 ? b0 : a0;
        cv.u[1] = hi2 ? b1 : a1;
        cv.u[2] = hi2 ? b2 : a2;
        cv.u[3] = hi2 ? b3 : a3;
        ap[kc] = cv.v;
    }
    // O^T += V^T P^T
#pragma unroll
    for (int nd = 0; nd < 4; ++nd) {
        ov[nd] = __builtin_amdgcn_mfma_f32_16x16x32_bf16(av0[nd], ap[0], ov[nd], 0, 0, 0);
        ov[nd] = __builtin_amdgcn_mfma_f32_16x16x32_bf16(av1[nd], ap[1], ov[nd], 0, 0, 0);
    }
}

__device__ __forceinline__ void store_out(const f32x4 (&ov)[4], float lrun,
                                          long rowbase, int qb0, int h,
                                          int lo, int hi, short* __restrict__ y) {
    float inv = 1.0f / lrun;
    long row = (rowbase + qb0 + lo) * 768 + h * 64;
#pragma unroll
    for (int nd = 0; nd < 4; ++nd)
#pragma unroll
        for (int j2 = 0; j2 < 2; ++j2) {
            unsigned pv = pk_bf16(ov[nd][2 * j2] * inv, ov[nd][2 * j2 + 1] * inv);
            *(unsigned*)(y + row + nd * 16 + hi * 4 + 2 * j2) = pv;
        }
}

// grid 1536 (d = qp*192 + g -> d%8 == g%8: all q-blocks of a head on one XCD).
// Block = 4 waves sharing (b,h); waves own paired q-fragments (qp, 15-qp) -> 17 staged
// tiles/block, uniform. K/V tiles DMA-staged once per block (global_load_lds, swizzled),
// double-buffered, 2-phase pipeline.
__global__ __launch_bounds__(256) void flash_attn7(const short* __restrict__ qpk,
                                                   const short* __restrict__ kpk,
                                                   const short* __restrict__ vtg,
                                                   short* __restrict__ y) {
    __shared__ short Kb[2][4096];
    __shared__ short Vb[2][4096];

    int d = blockIdx.x;
    int qp = d / 192, g = d % 192;
    int h = g % 12, b = g / 12;
    int tid = threadIdx.x, lane = tid & 63, w = tid >> 6;
    int lo = lane & 15, hi = lane >> 4, hi2 = hi >> 1;
    long rowbase = (long)b * 1024;
    const short* kb_g = kpk + (long)g * 65536;
    const short* vt_g = vtg + (long)g * 65536;
    int sA = ((hi & 1) * 2) * 16 + lo, sB = sA + 16;

    // staging geometry: wave w covers rows w*8..w*8+7 (+32), 8 chunks of 16B per row.
    int rl = lane >> 3;                       // row-in-group 0..7
    int cs8 = (((lane & 7) ^ rl)) * 8;        // pre-swizzled source chunk (shorts)
    int r0 = w * 8 + rl;                      // tile rows r0, r0+32
    // swizzled LDS read offsets (shorts): slot = chunk ^ (row&7); row&7 == lo&7 for frag rows
    int sl0 = (hi ^ (lo & 7)) * 8;
    int sl1 = ((hi + 4) ^ (lo & 7)) * 8;

    int qbA = qp * 64 + w * 16;
    int qbB = (15 - qp) * 64 + w * 16;

    // fragment state (reused across the two phases)
    f32x4 ov[4];
    float mrun = -3.0e38f, lrun = 0.f;
#pragma unroll
    for (int nd = 0; nd < 4; ++nd) ov[nd] = (f32x4){0.f, 0.f, 0.f, 0.f};
    s16x8 bq0, bq1;
    {
        const short* qrow = qpk + ((long)g * 1024 + qbA + lo) * 64;
        bq0 = *(const s16x8*)(qrow + hi * 8);
        bq1 = *(const s16x8*)(qrow + 32 + hi * 8);
    }

#define STAGE(kv0_, buf_)                                                                    \
    do {                                                                                     \
        _Pragma("unroll")                                                                    \
        for (int i_ = 0; i_ < 2; ++i_) {                                                     \
            int r_ = i_ * 32 + r0;                                                           \
            __builtin_amdgcn_global_load_lds(                                                \
                (const AS1 void*)(kb_g + (long)((kv0_) + r_) * 64 + cs8),                    \
                (AS3 void*)(Kb[buf_] + (i_ * 32 + w * 8) * 64), 16, 0, 0);                   \
            __builtin_amdgcn_global_load_lds(                                                \
                (const AS1 void*)(vt_g + (long)r_ * 1024 + (kv0_) + cs8),                    \
                (AS3 void*)(Vb[buf_] + (i_ * 32 + w * 8) * 64), 16, 0, 0);                   \
        }                                                                                    \
    } while (0)

    // prologue: stage tile 0 (frag A, kv0=0) into buf 0
    STAGE(0, 0);
    __syncthreads();

    int cur = 0;
    for (int u = 0; u < 17; ++u) {
        int nu = u + 1;
        if (nu < 17) {
            int nkv0 = (nu <= qp) ? nu * 64 : (nu - qp - 1) * 64;
            STAGE(nkv0, cur ^ 1);
        }
        bool phaseA = (u <= qp);
        int kv0 = phaseA ? u * 64 : (u - qp - 1) * 64;
        int qb0 = phaseA ? qbA : qbB;
        bool diag = phaseA ? (u == qp) : (u == 16);
        attn_tile(Kb[cur], Vb[cur], kv0, qb0, diag, bq0, bq1, ov, mrun, lrun,
                  lo, hi, hi2, sA, sB, sl0, sl1);
        if (phaseA && u == qp) {
            // epilogue for fragment A, then switch state to fragment B
            store_out(ov, lrun, rowbase, qbA, h, lo, hi, y);
            const short* qrow = qpk + ((long)g * 1024 + qbB + lo) * 64;
            bq0 = *(const s16x8*)(qrow + hi * 8);
            bq1 = *(const s16x8*)(qrow + 32 + hi * 8);
#pragma unroll
            for (int nd = 0; nd < 4; ++nd) ov[nd] = (f32x4){0.f, 0.f, 0.f, 0.f};
            mrun = -3.0e38f; lrun = 0.f;
        }
        __syncthreads();   // drains DMA (vmcnt) + orders buffer reuse
        cur ^= 1;
    }
    store_out(ov, lrun, rowbase, qbB, h, lo, hi, y);
#undef STAGE
}

// ---------------- launch ----------------

extern "C" void kernel_launch(void* const* d_in, const int* in_sizes, int n_in,
                              void* d_out, int out_size, void* d_ws, size_t ws_size,
                              hipStream_t stream) {
    const float* x      = (const float*)d_in[0];
    const float* w_attn = (const float*)d_in[1];
    const float* b_attn = (const float*)d_in[2];
    const float* w_proj = (const float*)d_in[3];
    const float* b_proj = (const float*)d_in[4];

    char* ws = (char*)d_ws;
    short* x_bf = (short*)ws;                      // 25165824 B (aliased as vt after gemm1)
    short* qpk  = (short*)(ws + 25165824);         // 25165824 B  q packed [g][1024][64]
    short* kpk  = (short*)(ws + 50331648);         // 25165824 B  k packed [g][1024][64]
    short* vpk  = (short*)(ws + 75497472);         // 25165824 B  v packed [g][1024][64]
    short* yb   = (short*)(ws + 100663296);        // 25165824 B
    short* waT  = (short*)(ws + 125829120);        // 3538944 B
    short* wpT  = (short*)(ws + 129368064);        // 1179648 B
    short* vt   = x_bf;                            // alias: x_bf dead after gemm1

    // x -> bf16
    convert_f32_bf16<<<dim3(12288), dim3(256), 0, stream>>>(x, x_bf, 3145728);
    // weight transposes (to [N][K] bf16)
    transpose_w<<<dim3(12, 36), dim3(256), 0, stream>>>(w_attn, waT, 768, 2304);
    transpose_w<<<dim3(12, 12), dim3(256), 0, stream>>>(w_proj, wpT, 768, 768);
    // QKV projection (+bias), scatter to per-head packed q/k/v (q scaled by 1/8*log2e)
    gemm_bt<1><<<dim3(18, 128), dim3(256), 0, stream>>>(x_bf, waT, b_attn,
                                                        (float*)nullptr, qpk, kpk, vpk,
                                                        16384, 2304, 768);
    // V^T per head
    transpose_vp<<<dim3(16, 192), dim3(256), 0, stream>>>(vpk, vt);
    // causal flash attention (DMA-staged shared KV tiles)
    flash_attn7<<<dim3(1536), dim3(256), 0, stream>>>(qpk, kpk, vt, yb);
    // output projection -> fp32
    gemm_bt<0><<<dim3(6, 128), dim3(256), 0, stream>>>(yb, wpT, b_proj,
                                                       (float*)d_out, (short*)nullptr,
                                                       (short*)nullptr, (short*)nullptr,
                                                       16384, 768, 768);
}